// Round 12
// baseline (160.926 us; speedup 1.0000x reference)
//
#include <hip/hip_runtime.h>
#include <hip/hip_bf16.h>

// InfoNCE loss, B=8192, D=128, T=0.1.
// R12 = INSTRUMENTED ABLATION ROUND (score sacrificed for counter evidence).
// Three sim variants, each double-pass (2x duration -> visible in rocprof
// top-5 above the ~40us harness poison fills), launched 0,1,2; variant 2
// (R5-exact epilogue) runs last and owns the validated output.
//   sim<0>: skeleton (stage+ds_read+MFMA, no epilogue)  -> pipeline floor
//   sim<1>: same VALU count as R5, 4-way ILP chains + hoisted labv -> latency probe
//   sim<2>: R5-exact serial epilogue                     -> baseline
//
// ws layout:
//   pos_part f32[32][8192]  1MB   (sim)
//   all_part f32[32][8192]  1MB   (sim)
//   lab32    i32[8192]            (prep)
//   diag     f32[8192]            (prep)
//   lab8p    u8[8192]             (prep; 32-row-group permuted label bytes)
//   fin_s    f32[32], fin_c f32[32], ticket u32 (fin; ticket zeroed by prep)
//   Ebf      bf16[8192*128] 2MB   (prep; unit rows, j-side / LDS)
//   Ebf2     bf16[8192*128] 2MB   (prep; K_SCALE-scaled rows, i-side regs)

#define B_ROWS 8192
#define D_DIM 128
#define K_SCALE 14.426950408889634f  // log2(e)/0.1
#define JSPLIT 32
#define JCHUNK (B_ROWS / JSPLIT)  // 256
#define TILE_J 64
#define NT (JCHUNK / TILE_J)  // 4
#define BM 256                // i-rows per block = 4 waves x 64
#define NPASS 2               // visibility doubling

typedef __attribute__((ext_vector_type(8))) short bf16x8;
typedef __attribute__((ext_vector_type(16))) float f32x16;
typedef __attribute__((ext_vector_type(4))) unsigned int u32x4;
typedef unsigned int u32;
typedef unsigned long long u64;

static __device__ __forceinline__ unsigned short bf16_bits(float x) {
  __hip_bfloat16 h = __float2bfloat16(x);
  unsigned short u;
  __builtin_memcpy(&u, &h, 2);
  return u;
}
static __device__ __forceinline__ float f32_from_bits(u32 b) {
  float f;
  __builtin_memcpy(&f, &b, 4);
  return f;
}
static __device__ __forceinline__ float bf16f(unsigned short u) {
  return f32_from_bits((u32)u << 16);
}

__global__ __launch_bounds__(256) void prep_kernel(
    const float* __restrict__ E, const long long* __restrict__ labels,
    __hip_bfloat16* __restrict__ Ebf, __hip_bfloat16* __restrict__ Ebf2,
    int* __restrict__ lab32, unsigned char* __restrict__ lab8p,
    float* __restrict__ diag, u32* __restrict__ ticket) {
  if (blockIdx.x == 0 && threadIdx.x == 0) *ticket = 0u;
  const int wid = threadIdx.x >> 6, lane = threadIdx.x & 63;
  const int row = blockIdx.x * 4 + wid;
  const float2 v = *(const float2*)(E + (u64)row * D_DIM + lane * 2);
  float ss = v.x * v.x + v.y * v.y;
#pragma unroll
  for (int m = 1; m < 64; m <<= 1) ss += __shfl_xor(ss, m);
  const float scale = 1.0f / fmaxf(sqrtf(ss), 1e-12f);
  const unsigned short bx = bf16_bits(v.x * scale);
  const unsigned short by = bf16_bits(v.y * scale);
  ((u32*)Ebf)[(u64)row * (D_DIM / 2) + lane] = ((u32)by << 16) | bx;
  const float fx = bf16f(bx), fy = bf16f(by);
  const unsigned short axb = bf16_bits(fx * K_SCALE);
  const unsigned short ayb = bf16_bits(fy * K_SCALE);
  ((u32*)Ebf2)[(u64)row * (D_DIM / 2) + lane] = ((u32)ayb << 16) | axb;
  float dot = bf16f(axb) * fx + bf16f(ayb) * fy;
#pragma unroll
  for (int m = 1; m < 64; m <<= 1) dot += __shfl_xor(dot, m);
  if (lane == 0) diag[row] = __builtin_amdgcn_exp2f(dot);

  const int gtid = blockIdx.x * 256 + threadIdx.x;
  if (gtid < B_ROWS) {
    const int lab = (int)labels[gtid];
    lab32[gtid] = lab;
    const int local = gtid & 31;
    const int h = (local >> 2) & 1;
    const int r = (local & 3) + 4 * (local >> 3);
    lab8p[(gtid & ~31) + h * 16 + r] = (unsigned char)lab;
  }
}

// MODE 0 = skeleton, 1 = ILP epilogue, 2 = R5 serial epilogue.
template <int MODE>
__global__ __launch_bounds__(256) void sim_kernel(
    const __hip_bfloat16* __restrict__ Ebf,
    const __hip_bfloat16* __restrict__ Ebf2, const int* __restrict__ lab32,
    const unsigned char* __restrict__ lab8p, float* __restrict__ pos_part,
    float* __restrict__ all_part) {
  __shared__ __align__(16) unsigned char lds[2][TILE_J * 256];

  const int t = threadIdx.x;
  const int wid = t >> 6, lane = t & 63;
  const int l31 = lane & 31, hi = lane >> 5;
  const int i0w = blockIdx.x * BM + wid * 64;
  const int jbase0 = blockIdx.y * JCHUNK;

  // two register-resident pre-scaled i-side fragment sets, pinned vs remat
  bf16x8 ifragA[8], ifragB[8];
  {
    const __hip_bfloat16* srcA = Ebf2 + (u64)(i0w + l31) * D_DIM + hi * 8;
    const __hip_bfloat16* srcB = srcA + 32 * D_DIM;
#pragma unroll
    for (int ks = 0; ks < 8; ++ks) {
      ifragA[ks] = *(const bf16x8*)(srcA + ks * 16);
      ifragB[ks] = *(const bf16x8*)(srcB + ks * 16);
      asm volatile("" : "+v"(ifragA[ks]));
      asm volatile("" : "+v"(ifragB[ks]));
    }
  }
  const int labiA = lab32[i0w + l31];
  const int labiB = lab32[i0w + 32 + l31];

  // swizzled LDS read addressing (R5-verified)
  const u32 key = lane & 15;
  const u32 M = (key & 14) << 4;
  const u32 base2 = (u32)(l31 * 256) + (((hi ^ (key & 1)) & 1) << 4);

  // stateless staging (R9-verified): global slot (sl^(i*4+l4)) = sx4^(i<<6)
  const unsigned char* gb = (const unsigned char*)Ebf;
  const int l4 = lane >> 4, sl = lane & 15;
  const u32 sx4 = (u32)(sl ^ l4) << 4;
  const u32 jrow0 = (u32)(jbase0 + wid * 16 + l4);

  auto stage = [&](int buf, int tile) {
#pragma unroll
    for (int i = 0; i < 4; ++i) {
      const u32 goff =
          (jrow0 + (u32)(tile * TILE_J + i * 4)) * 256u + (sx4 ^ (u32)(i << 6));
      __builtin_amdgcn_global_load_lds(
          (const __attribute__((address_space(1))) u32*)(gb + goff),
          (__attribute__((address_space(3)))
               u32*)(&lds[buf][wid * 4096 + i * 1024]),
          16, 0, 0);
    }
  };

  for (int pass = 0; pass < NPASS; ++pass) {
    float posA = 0.f, posB = 0.f, allA = 0.f, allB = 0.f;
    float aA[4] = {}, aB[4] = {}, qA[4] = {}, qB[4] = {};  // MODE 1 chains

    stage(0, 0);
    __syncthreads();

    for (int tile = 0; tile < NT; ++tile) {
      const int cur = tile & 1;
      if (tile + 1 < NT) stage(cur ^ 1, tile + 1);
      const int jbase = jbase0 + tile * TILE_J;
      const unsigned char* lbuf = lds[cur];
#pragma unroll
      for (int jsub = 0; jsub < 2; ++jsub) {
        u32x4 labvE = {};
        if constexpr (MODE == 1)  // hoist label load above MFMAs
          labvE = *(const u32x4*)(lab8p + jbase + jsub * 32 + hi * 16);
        f32x16 acc0 = {}, acc1 = {};
#pragma unroll
        for (int ks = 0; ks < 8; ++ks) {
          bf16x8 jfrag = *(const bf16x8*)(lbuf + base2 +
                                          (((u32)(ks << 5)) ^ M) +
                                          jsub * 8192);
          acc0 = __builtin_amdgcn_mfma_f32_32x32x16_bf16(jfrag, ifragA[ks],
                                                         acc0, 0, 0, 0);
          acc1 = __builtin_amdgcn_mfma_f32_32x32x16_bf16(jfrag, ifragB[ks],
                                                         acc1, 0, 0, 0);
        }
        if constexpr (MODE == 0) {
          // keep MFMA tuples live (single-element use keeps the full MFMA)
          allA += acc0[0];
          allB += acc1[0];
        } else if constexpr (MODE == 1) {
#pragma unroll
          for (int r = 0; r < 16; ++r) {
            const int labj = (int)((labvE[r >> 2] >> ((r & 3) * 8)) & 0xff);
            const float p0 = __builtin_amdgcn_exp2f(acc0[r]);
            const float p1 = __builtin_amdgcn_exp2f(acc1[r]);
            aA[r & 3] += p0;
            aB[r & 3] += p1;
            qA[r & 3] += (labj == labiA) ? p0 : 0.f;
            qB[r & 3] += (labj == labiB) ? p1 : 0.f;
          }
        } else {
          const u32x4 labv =
              *(const u32x4*)(lab8p + jbase + jsub * 32 + hi * 16);
#pragma unroll
          for (int r = 0; r < 16; ++r) {
            const int labj = (int)((labv[r >> 2] >> ((r & 3) * 8)) & 0xff);
            const float p0 = __builtin_amdgcn_exp2f(acc0[r]);
            const float p1 = __builtin_amdgcn_exp2f(acc1[r]);
            allA += p0;
            allB += p1;
            posA += (labj == labiA) ? p0 : 0.f;
            posB += (labj == labiB) ? p1 : 0.f;
          }
        }
      }
      __syncthreads();
    }

    if constexpr (MODE == 1) {
      allA = (aA[0] + aA[1]) + (aA[2] + aA[3]);
      allB = (aB[0] + aB[1]) + (aB[2] + aB[3]);
      posA = (qA[0] + qA[1]) + (qA[2] + qA[3]);
      posB = (qB[0] + qB[1]) + (qB[2] + qB[3]);
    }
    posA += __shfl_xor(posA, 32);
    allA += __shfl_xor(allA, 32);
    posB += __shfl_xor(posB, 32);
    allB += __shfl_xor(allB, 32);
    if (hi == 0) {
      const u64 off = (u64)blockIdx.y * B_ROWS;
      pos_part[off + i0w + l31] = posA;
      all_part[off + i0w + l31] = allA;
      pos_part[off + i0w + 32 + l31] = posB;
      all_part[off + i0w + 32 + l31] = allB;
    }
  }
}

__global__ __launch_bounds__(256) void fin_kernel(
    const float* __restrict__ pos_part, const float* __restrict__ all_part,
    const float* __restrict__ diag, float* __restrict__ fin_s,
    float* __restrict__ fin_c, u32* __restrict__ ticket,
    float* __restrict__ out) {
  const int row = blockIdx.x * 256 + threadIdx.x;
  float ps = 0.f, as_ = 0.f;
#pragma unroll 8
  for (int js = 0; js < JSPLIT; ++js) {
    ps += pos_part[(u64)js * B_ROWS + row];
    as_ += all_part[(u64)js * B_ROWS + row];
  }
  const float d = diag[row];
  ps -= d;
  as_ -= d;
  float s = 0.f, c = 0.f;
  if (ps > 0.f) {
    s = logf(as_) - logf(ps);
    c = 1.f;
  }
#pragma unroll
  for (int m = 1; m < 64; m <<= 1) {
    s += __shfl_xor(s, m);
    c += __shfl_xor(c, m);
  }
  __shared__ float ls[4], lc[4];
  const int wid = threadIdx.x >> 6, lane = threadIdx.x & 63;
  if (lane == 0) {
    ls[wid] = s;
    lc[wid] = c;
  }
  __syncthreads();
  if (threadIdx.x == 0) {
    __hip_atomic_store(&fin_s[blockIdx.x], ls[0] + ls[1] + ls[2] + ls[3],
                       __ATOMIC_RELEASE, __HIP_MEMORY_SCOPE_AGENT);
    __hip_atomic_store(&fin_c[blockIdx.x], lc[0] + lc[1] + lc[2] + lc[3],
                       __ATOMIC_RELEASE, __HIP_MEMORY_SCOPE_AGENT);
    const u32 tk = __hip_atomic_fetch_add(ticket, 1u, __ATOMIC_ACQ_REL,
                                          __HIP_MEMORY_SCOPE_AGENT);
    if (tk == 31u) {
      float ts = 0.f, tc = 0.f;
      for (int b = 0; b < 32; ++b) {
        ts += __hip_atomic_load(&fin_s[b], __ATOMIC_ACQUIRE,
                                __HIP_MEMORY_SCOPE_AGENT);
        tc += __hip_atomic_load(&fin_c[b], __ATOMIC_ACQUIRE,
                                __HIP_MEMORY_SCOPE_AGENT);
      }
      out[0] = ts / fmaxf(tc, 1.0f);
    }
  }
}

extern "C" void kernel_launch(void* const* d_in, const int* in_sizes, int n_in,
                              void* d_out, int out_size, void* d_ws,
                              size_t ws_size, hipStream_t stream) {
  const float* E = (const float*)d_in[0];
  const long long* labels = (const long long*)d_in[1];

  float* pos_part = (float*)d_ws;                          // 32*8192
  float* all_part = pos_part + JSPLIT * B_ROWS;            // 32*8192
  int* lab32 = (int*)(all_part + JSPLIT * B_ROWS);         // 8192
  float* diag = (float*)(lab32 + B_ROWS);                  // 8192
  unsigned char* lab8p = (unsigned char*)(diag + B_ROWS);  // 8192
  float* fin_s = (float*)(lab8p + B_ROWS);                 // 32
  float* fin_c = fin_s + 32;                               // 32
  u32* ticket = (u32*)(fin_c + 32);                        // 1 (+pad)
  __hip_bfloat16* Ebf = (__hip_bfloat16*)(ticket + 4);
  __hip_bfloat16* Ebf2 = Ebf + (u64)B_ROWS * D_DIM;

  const dim3 g(B_ROWS / BM, JSPLIT);
  prep_kernel<<<B_ROWS / 4, 256, 0, stream>>>(E, labels, Ebf, Ebf2, lab32,
                                              lab8p, diag, ticket);
  sim_kernel<0><<<g, 256, 0, stream>>>(Ebf, Ebf2, lab32, lab8p, pos_part,
                                       all_part);
  sim_kernel<1><<<g, 256, 0, stream>>>(Ebf, Ebf2, lab32, lab8p, pos_part,
                                       all_part);
  sim_kernel<2><<<g, 256, 0, stream>>>(Ebf, Ebf2, lab32, lab8p, pos_part,
                                       all_part);
  fin_kernel<<<B_ROWS / 256, 256, 0, stream>>>(pos_part, all_part, diag,
                                               fin_s, fin_c, ticket,
                                               (float*)d_out);
}

// Round 13
// 86.151 us; speedup vs baseline: 1.8680x; 1.8680x over previous
//
#include <hip/hip_runtime.h>
#include <hip/hip_bf16.h>

// InfoNCE loss, B=8192, D=128, T=0.1.
// R13: R12's ablation proved the per-element epilogue (exp2+label cmp+sel+
// adds over 67M elements) is ~90% of sim (skeleton ~4.5us/pass vs full
// ~34.5us/pass; ILP restructure changed nothing). Split the label work out:
//   - sim_all: epilogue = exp2 + pairwise tree-sum ONLY (2 ops/elem).
//   - cls_kernel: deterministic per-class member lists (ballot/popc).
//   - pos_kernel: exp-sums over matching pairs only (~671K elems = 1%),
//     MFMA on member-gathered rows, i!=j masked, direct per-row store.
//   - fin: ps = pos_arr (diag-free by construction); all -= diag.
//
// ws layout:
//   pos_arr  f32[8192]            (pos_kernel; every row written once)
//   all_part f32[32][8192]  1MB   (sim_all)
//   lab32    i32[8192]            (prep)
//   diag     f32[8192]            (prep)
//   members  u16[100][256]        (cls)
//   cnt      i32[128]             (cls)
//   fin_s    f32[32], fin_c f32[32], ticket u32 (fin; ticket zeroed by prep)
//   Ebf      bf16[8192*128] 2MB   (prep; unit rows, j-side)
//   Ebf2     bf16[8192*128] 2MB   (prep; K_SCALE-scaled rows, i-side)

#define B_ROWS 8192
#define D_DIM 128
#define NCLS 100
#define MAXM 256
#define K_SCALE 14.426950408889634f  // log2(e)/0.1
#define JSPLIT 32
#define JCHUNK (B_ROWS / JSPLIT)  // 256
#define TILE_J 64
#define NT (JCHUNK / TILE_J)  // 4
#define BM 256                // i-rows per block = 4 waves x 64

typedef __attribute__((ext_vector_type(8))) short bf16x8;
typedef __attribute__((ext_vector_type(16))) float f32x16;
typedef unsigned short u16;
typedef unsigned int u32;
typedef unsigned long long u64;

static __device__ __forceinline__ unsigned short bf16_bits(float x) {
  __hip_bfloat16 h = __float2bfloat16(x);
  unsigned short u;
  __builtin_memcpy(&u, &h, 2);
  return u;
}
static __device__ __forceinline__ float f32_from_bits(u32 b) {
  float f;
  __builtin_memcpy(&f, &b, 4);
  return f;
}
static __device__ __forceinline__ float bf16f(unsigned short u) {
  return f32_from_bits((u32)u << 16);
}

__global__ __launch_bounds__(256) void prep_kernel(
    const float* __restrict__ E, const long long* __restrict__ labels,
    __hip_bfloat16* __restrict__ Ebf, __hip_bfloat16* __restrict__ Ebf2,
    int* __restrict__ lab32, float* __restrict__ diag,
    u32* __restrict__ ticket) {
  if (blockIdx.x == 0 && threadIdx.x == 0) *ticket = 0u;
  const int wid = threadIdx.x >> 6, lane = threadIdx.x & 63;
  const int row = blockIdx.x * 4 + wid;
  const float2 v = *(const float2*)(E + (u64)row * D_DIM + lane * 2);
  float ss = v.x * v.x + v.y * v.y;
#pragma unroll
  for (int m = 1; m < 64; m <<= 1) ss += __shfl_xor(ss, m);
  const float scale = 1.0f / fmaxf(sqrtf(ss), 1e-12f);
  const unsigned short bx = bf16_bits(v.x * scale);
  const unsigned short by = bf16_bits(v.y * scale);
  ((u32*)Ebf)[(u64)row * (D_DIM / 2) + lane] = ((u32)by << 16) | bx;
  const float fx = bf16f(bx), fy = bf16f(by);
  const unsigned short axb = bf16_bits(fx * K_SCALE);
  const unsigned short ayb = bf16_bits(fy * K_SCALE);
  ((u32*)Ebf2)[(u64)row * (D_DIM / 2) + lane] = ((u32)ayb << 16) | axb;
  float dot = bf16f(axb) * fx + bf16f(ayb) * fy;
#pragma unroll
  for (int m = 1; m < 64; m <<= 1) dot += __shfl_xor(dot, m);
  if (lane == 0) diag[row] = __builtin_amdgcn_exp2f(dot);

  const int gtid = blockIdx.x * 256 + threadIdx.x;
  if (gtid < B_ROWS) lab32[gtid] = (int)labels[gtid];
}

// Per-class member lists, ascending, deterministic. 1 wave per class.
__global__ __launch_bounds__(64) void cls_kernel(const int* __restrict__ lab32,
                                                 u16* __restrict__ members,
                                                 int* __restrict__ cnt) {
  const int c = blockIdx.x;
  const int lane = threadIdx.x;
  u16* M = members + c * MAXM;
  int base = 0;
  for (int chunk = 0; chunk < B_ROWS; chunk += 64) {
    const int lab = lab32[chunk + lane];
    const unsigned long long mask = __ballot(lab == c);
    if (lab == c) {
      const int pref = __popcll(mask & ((1ull << lane) - 1ull));
      if (base + pref < MAXM) M[base + pref] = (u16)(chunk + lane);
    }
    base += __popcll(mask);
  }
  if (lane == 0) cnt[c] = (base < MAXM) ? base : MAXM;
}

// pos sums over matching-label pairs only. 1 block per class; waves own
// 32-member i-chunks; j-fragments gathered straight from global (L2, tiny).
// 32x32x16 MFMA swapped: i = lane&31, j = (r&3)+8*(r>>2)+4*(lane>>5).
__global__ __launch_bounds__(256) void pos_kernel(
    const __hip_bfloat16* __restrict__ Ebf,
    const __hip_bfloat16* __restrict__ Ebf2, const u16* __restrict__ members,
    const int* __restrict__ cnt, float* __restrict__ pos_arr) {
  const int c = blockIdx.x;
  const int n = cnt[c];
  const int t = threadIdx.x;
  const int wid = t >> 6, lane = t & 63;
  const int l31 = lane & 31, hi = lane >> 5;
  const u16* M = members + c * MAXM;

  for (int ic = wid * 32; ic < n; ic += 128) {
    const int ipos = ic + l31;
    const int irow = (ipos < n) ? (int)M[ipos] : (int)M[0];
    bf16x8 ifr[8];
    {
      const __hip_bfloat16* src = Ebf2 + (u64)irow * D_DIM + hi * 8;
#pragma unroll
      for (int ks = 0; ks < 8; ++ks) ifr[ks] = *(const bf16x8*)(src + ks * 16);
    }
    float posv = 0.f;
    for (int jc = 0; jc < n; jc += 32) {
      const int jposl = jc + l31;
      const int jrow = (jposl < n) ? (int)M[jposl] : (int)M[0];
      const __hip_bfloat16* jsrc = Ebf + (u64)jrow * D_DIM + hi * 8;
      f32x16 acc = {};
#pragma unroll
      for (int ks = 0; ks < 8; ++ks) {
        const bf16x8 jf = *(const bf16x8*)(jsrc + ks * 16);
        acc = __builtin_amdgcn_mfma_f32_32x32x16_bf16(jf, ifr[ks], acc, 0, 0,
                                                      0);
      }
#pragma unroll
      for (int r = 0; r < 16; ++r) {
        const int jpos = jc + (r & 3) + 8 * (r >> 2) + 4 * hi;
        const bool valid = (jpos < n) && (ipos < n) && (jpos != ipos);
        posv += valid ? __builtin_amdgcn_exp2f(acc[r]) : 0.f;
      }
    }
    posv += __shfl_xor(posv, 32);  // combine hi halves (disjoint j)
    if (hi == 0 && ipos < n) pos_arr[(int)M[ipos]] = posv;
  }
}

// all_sum only: epilogue = exp2 + pairwise tree-sum (no labels).
// R5 structure: 4 waves x 64 i-rows, dbuf LDS, XOR swizzle, grid (32,32).
__global__ __launch_bounds__(256) void sim_kernel(
    const __hip_bfloat16* __restrict__ Ebf,
    const __hip_bfloat16* __restrict__ Ebf2, float* __restrict__ all_part) {
  __shared__ __align__(16) unsigned char lds[2][TILE_J * 256];

  const int t = threadIdx.x;
  const int wid = t >> 6, lane = t & 63;
  const int l31 = lane & 31, hi = lane >> 5;
  const int i0w = blockIdx.x * BM + wid * 64;
  const int jbase0 = blockIdx.y * JCHUNK;

  bf16x8 ifragA[8], ifragB[8];
  {
    const __hip_bfloat16* srcA = Ebf2 + (u64)(i0w + l31) * D_DIM + hi * 8;
    const __hip_bfloat16* srcB = srcA + 32 * D_DIM;
#pragma unroll
    for (int ks = 0; ks < 8; ++ks) {
      ifragA[ks] = *(const bf16x8*)(srcA + ks * 16);
      ifragB[ks] = *(const bf16x8*)(srcB + ks * 16);
      asm volatile("" : "+v"(ifragA[ks]));
      asm volatile("" : "+v"(ifragB[ks]));
    }
  }

  const u32 key = lane & 15;
  const u32 M = (key & 14) << 4;
  const u32 base2 = (u32)(l31 * 256) + (((hi ^ (key & 1)) & 1) << 4);

  const unsigned char* gb = (const unsigned char*)Ebf;
  const int l4 = lane >> 4, sl = lane & 15;
  const u32 sx4 = (u32)(sl ^ l4) << 4;
  const u32 jrow0 = (u32)(jbase0 + wid * 16 + l4);

  auto stage = [&](int buf, int tile) {
#pragma unroll
    for (int i = 0; i < 4; ++i) {
      const u32 goff =
          (jrow0 + (u32)(tile * TILE_J + i * 4)) * 256u + (sx4 ^ (u32)(i << 6));
      __builtin_amdgcn_global_load_lds(
          (const __attribute__((address_space(1))) u32*)(gb + goff),
          (__attribute__((address_space(3)))
               u32*)(&lds[buf][wid * 4096 + i * 1024]),
          16, 0, 0);
    }
  };

  float allA = 0.f, allB = 0.f;

  stage(0, 0);
  __syncthreads();

  for (int tile = 0; tile < NT; ++tile) {
    const int cur = tile & 1;
    if (tile + 1 < NT) stage(cur ^ 1, tile + 1);
    const unsigned char* lbuf = lds[cur];
#pragma unroll
    for (int jsub = 0; jsub < 2; ++jsub) {
      f32x16 acc0 = {}, acc1 = {};
#pragma unroll
      for (int ks = 0; ks < 8; ++ks) {
        bf16x8 jfrag = *(const bf16x8*)(lbuf + base2 +
                                        (((u32)(ks << 5)) ^ M) + jsub * 8192);
        acc0 = __builtin_amdgcn_mfma_f32_32x32x16_bf16(jfrag, ifragA[ks], acc0,
                                                       0, 0, 0);
        acc1 = __builtin_amdgcn_mfma_f32_32x32x16_bf16(jfrag, ifragB[ks], acc1,
                                                       0, 0, 0);
      }
      float pa[16], pb[16];
#pragma unroll
      for (int r = 0; r < 16; ++r) {
        pa[r] = __builtin_amdgcn_exp2f(acc0[r]);
        pb[r] = __builtin_amdgcn_exp2f(acc1[r]);
      }
#pragma unroll
      for (int m = 8; m >= 1; m >>= 1) {
#pragma unroll
        for (int r = 0; r < m; ++r) {
          pa[r] += pa[r + m];
          pb[r] += pb[r + m];
        }
      }
      allA += pa[0];
      allB += pb[0];
    }
    __syncthreads();
  }

  allA += __shfl_xor(allA, 32);
  allB += __shfl_xor(allB, 32);
  if (hi == 0) {
    const u64 off = (u64)blockIdx.y * B_ROWS;
    all_part[off + i0w + l31] = allA;
    all_part[off + i0w + 32 + l31] = allB;
  }
}

// fin: ps = pos_arr (diag-free), as = sum(all_part) - diag; last-block ticket.
__global__ __launch_bounds__(256) void fin_kernel(
    const float* __restrict__ pos_arr, const float* __restrict__ all_part,
    const float* __restrict__ diag, float* __restrict__ fin_s,
    float* __restrict__ fin_c, u32* __restrict__ ticket,
    float* __restrict__ out) {
  const int row = blockIdx.x * 256 + threadIdx.x;
  float as_ = 0.f;
#pragma unroll 8
  for (int js = 0; js < JSPLIT; ++js) as_ += all_part[(u64)js * B_ROWS + row];
  as_ -= diag[row];
  const float ps = pos_arr[row];
  float s = 0.f, c = 0.f;
  if (ps > 0.f) {
    s = logf(as_) - logf(ps);
    c = 1.f;
  }
#pragma unroll
  for (int m = 1; m < 64; m <<= 1) {
    s += __shfl_xor(s, m);
    c += __shfl_xor(c, m);
  }
  __shared__ float ls[4], lc[4];
  const int wid = threadIdx.x >> 6, lane = threadIdx.x & 63;
  if (lane == 0) {
    ls[wid] = s;
    lc[wid] = c;
  }
  __syncthreads();
  if (threadIdx.x == 0) {
    __hip_atomic_store(&fin_s[blockIdx.x], ls[0] + ls[1] + ls[2] + ls[3],
                       __ATOMIC_RELEASE, __HIP_MEMORY_SCOPE_AGENT);
    __hip_atomic_store(&fin_c[blockIdx.x], lc[0] + lc[1] + lc[2] + lc[3],
                       __ATOMIC_RELEASE, __HIP_MEMORY_SCOPE_AGENT);
    const u32 tk = __hip_atomic_fetch_add(ticket, 1u, __ATOMIC_ACQ_REL,
                                          __HIP_MEMORY_SCOPE_AGENT);
    if (tk == 31u) {
      float ts = 0.f, tc = 0.f;
      for (int b = 0; b < 32; ++b) {
        ts += __hip_atomic_load(&fin_s[b], __ATOMIC_ACQUIRE,
                                __HIP_MEMORY_SCOPE_AGENT);
        tc += __hip_atomic_load(&fin_c[b], __ATOMIC_ACQUIRE,
                                __HIP_MEMORY_SCOPE_AGENT);
      }
      out[0] = ts / fmaxf(tc, 1.0f);
    }
  }
}

extern "C" void kernel_launch(void* const* d_in, const int* in_sizes, int n_in,
                              void* d_out, int out_size, void* d_ws,
                              size_t ws_size, hipStream_t stream) {
  const float* E = (const float*)d_in[0];
  const long long* labels = (const long long*)d_in[1];

  float* pos_arr = (float*)d_ws;                       // 8192
  float* all_part = pos_arr + B_ROWS;                  // 32*8192
  int* lab32 = (int*)(all_part + JSPLIT * B_ROWS);     // 8192
  float* diag = (float*)(lab32 + B_ROWS);              // 8192
  u16* members = (u16*)(diag + B_ROWS);                // 100*256
  int* cnt = (int*)(members + NCLS * MAXM);            // 128
  float* fin_s = (float*)(cnt + 128);                  // 32
  float* fin_c = fin_s + 32;                           // 32
  u32* ticket = (u32*)(fin_c + 32);                    // 1 (+pad)
  __hip_bfloat16* Ebf = (__hip_bfloat16*)(ticket + 4);
  __hip_bfloat16* Ebf2 = Ebf + (u64)B_ROWS * D_DIM;

  prep_kernel<<<B_ROWS / 4, 256, 0, stream>>>(E, labels, Ebf, Ebf2, lab32,
                                              diag, ticket);
  cls_kernel<<<NCLS, 64, 0, stream>>>(lab32, members, cnt);
  pos_kernel<<<NCLS, 256, 0, stream>>>(Ebf, Ebf2, members, cnt, pos_arr);
  sim_kernel<<<dim3(B_ROWS / BM, JSPLIT), 256, 0, stream>>>(Ebf, Ebf2,
                                                            all_part);
  fin_kernel<<<B_ROWS / 256, 256, 0, stream>>>(pos_arr, all_part, diag, fin_s,
                                               fin_c, ticket, (float*)d_out);
}